// Round 4
// baseline (115.916 us; speedup 1.0000x reference)
//
#include <hip/hip_runtime.h>
#include <math.h>

// Barrier_Net: deep-sets net + barrier + global max-rescale.
// R1: LDS broadcast-bound (41 µs of per-CU ds_read). R2: wave-uniform x loads
// -> scalar-cache path, still ~40 µs. R3: runtime-indexed v_readlane, still
// ~40 µs — suspected waterfall lowering of SGPR-indexed readlane.
// R4: (a) FULL unroll so every readlane has an IMMEDIATE lane index
// (waterfall impossible); (b) single fused kernel: scale pass merged via
// fence+counter last-block pattern, removing one dispatch + graph gap.

#define GROWS 4
#define NBLOCKS (4096 / GROWS)   // 1024 blocks -> 4 blocks/CU, 16 waves/CU

__device__ __forceinline__ unsigned fkey(float f) {
    unsigned u = __float_as_uint(f);
    return (u & 0x80000000u) ? ~u : (u | 0x80000000u);
}
__device__ __forceinline__ float fkey_inv(unsigned k) {
    return __uint_as_float((k & 0x80000000u) ? (k & 0x7fffffffu) : ~k);
}
__device__ __forceinline__ float rlane_imm(float v, int i) {
    // i must be a compile-time constant at each call site (full unroll).
    return __uint_as_float(__builtin_amdgcn_readlane(__float_as_uint(v), i));
}

__global__ __launch_bounds__(256, 4) void barrier_net_fused(
    const float* __restrict__ x,
    const float* __restrict__ w1,  const float* __restrict__ b1,
    const float* __restrict__ w2,  const float* __restrict__ b2,
    const float* __restrict__ rw1, const float* __restrict__ rb1,
    const float* __restrict__ rw2, const float* __restrict__ rb2,
    float* __restrict__ out, unsigned* __restrict__ ws)  // ws[0]=key ws[1]=ctr
{
    __shared__ float sH[GROWS][264];     // H rows (padded)
    __shared__ float sXp[4][GROWS][68];  // [wave][row][o] phase-2 partials
    __shared__ float sP4[4][GROWS][2];   // [wave][row][c] phase-4 partials
    __shared__ float sbar[GROWS][2];     // barrier terms
    __shared__ float sa[GROWS * 2];      // final a for block max
    __shared__ int   sLast;

    const int tid = threadIdx.x;
    const int ln  = tid & 63;
    const int wv  = tid >> 6;
    const int b0  = blockIdx.x * GROWS;
    const int row = b0 + wv;             // wave <-> batch row
    const float4* __restrict__ x4 = (const float4*)(x + (size_t)row * 264);

    // Two coalesced lane-varying loads cover ALL x access for this row:
    // xr: lane ln holds neighbor-block n=ln; pv: lane ln holds n=ln+2.
    float4 xr = x4[ln];
    float4 pv = x4[ln + 2];

    // ---- phase 1: H[row][4ln..4ln+3] = sum_n relu(x_n . w1 + b1) ----
    float4 w1r0 = ((const float4*)(w1      ))[ln];
    float4 w1r1 = ((const float4*)(w1 + 256))[ln];
    float4 w1r2 = ((const float4*)(w1 + 512))[ln];
    float4 w1r3 = ((const float4*)(w1 + 768))[ln];
    float4 b1r  = ((const float4*)b1)[ln];
    float a0 = 0.f, a1 = 0.f, a2 = 0.f, a3 = 0.f;
    #define P1_STEP(X0, X1, X2, X3)                                        \
    do {                                                                   \
        float h0 = b1r.x, h1 = b1r.y, h2 = b1r.z, h3 = b1r.w;              \
        h0 = fmaf(X0, w1r0.x, h0); h1 = fmaf(X0, w1r0.y, h1);              \
        h2 = fmaf(X0, w1r0.z, h2); h3 = fmaf(X0, w1r0.w, h3);              \
        h0 = fmaf(X1, w1r1.x, h0); h1 = fmaf(X1, w1r1.y, h1);              \
        h2 = fmaf(X1, w1r1.z, h2); h3 = fmaf(X1, w1r1.w, h3);              \
        h0 = fmaf(X2, w1r2.x, h0); h1 = fmaf(X2, w1r2.y, h1);              \
        h2 = fmaf(X2, w1r2.z, h2); h3 = fmaf(X2, w1r2.w, h3);              \
        h0 = fmaf(X3, w1r3.x, h0); h1 = fmaf(X3, w1r3.y, h1);              \
        h2 = fmaf(X3, w1r3.z, h2); h3 = fmaf(X3, w1r3.w, h3);              \
        a0 += fmaxf(h0, 0.f); a1 += fmaxf(h1, 0.f);                        \
        a2 += fmaxf(h2, 0.f); a3 += fmaxf(h3, 0.f);                        \
    } while (0)

    // FULL unroll: n is a literal at every readlane -> immediate lane select.
    #pragma unroll
    for (int n = 0; n < 64; n++) {
        float X0 = rlane_imm(xr.x, n), X1 = rlane_imm(xr.y, n),
              X2 = rlane_imm(xr.z, n), X3 = rlane_imm(xr.w, n);
        P1_STEP(X0, X1, X2, X3);
    }
    {   // n = 64, 65 live in pv lanes 62, 63
        float X0 = rlane_imm(pv.x, 62), X1 = rlane_imm(pv.y, 62),
              X2 = rlane_imm(pv.z, 62), X3 = rlane_imm(pv.w, 62);
        P1_STEP(X0, X1, X2, X3);
        X0 = rlane_imm(pv.x, 63); X1 = rlane_imm(pv.y, 63);
        X2 = rlane_imm(pv.z, 63); X3 = rlane_imm(pv.w, 63);
        P1_STEP(X0, X1, X2, X3);
    }
    ((float4*)sH[wv])[ln] = make_float4(a0, a1, a2, a3);

    // ---- barrier term: lane ln <-> neighbor n = ln+2 (exactly 64) ----
    {
        float px = pv.x, py = pv.y;
        float d  = sqrtf(px * px + py * py);
        float t  = d - 0.15f;
        float inv = 1.0f / (t * t);
        float bx = -px * inv, by = -py * inv;
        #pragma unroll
        for (int m = 32; m >= 1; m >>= 1) {
            bx += __shfl_xor(bx, m);
            by += __shfl_xor(by, m);
        }
        if (ln == 0) { sbar[wv][0] = bx; sbar[wv][1] = by; }
    }
    __syncthreads();

    // ---- phase 2: X[r][o] = sum_k H[r][k] w2[k][o] + 66*b2[o] ----
    float Hq0 = sH[0][(wv << 6) + ln];
    float Hq1 = sH[1][(wv << 6) + ln];
    float Hq2 = sH[2][(wv << 6) + ln];
    float Hq3 = sH[3][(wv << 6) + ln];
    {
        float xp0 = 0.f, xp1 = 0.f, xp2 = 0.f, xp3 = 0.f;
        const float* w2q = w2 + (wv << 12);
        #pragma unroll   // full: immediate lane selects
        for (int i = 0; i < 64; i++) {
            float wv2 = w2q[(i << 6) + ln];   // coalesced; L2-resident
            xp0 = fmaf(rlane_imm(Hq0, i), wv2, xp0);
            xp1 = fmaf(rlane_imm(Hq1, i), wv2, xp1);
            xp2 = fmaf(rlane_imm(Hq2, i), wv2, xp2);
            xp3 = fmaf(rlane_imm(Hq3, i), wv2, xp3);
        }
        sXp[wv][0][ln] = xp0; sXp[wv][1][ln] = xp1;
        sXp[wv][2][ln] = xp2; sXp[wv][3][ln] = xp3;
    }
    __syncthreads();

    // every wave folds the 4 partials -> X[r][ln] in registers
    float bb = 66.0f * b2[ln];
    float Xf0 = sXp[0][0][ln] + sXp[1][0][ln] + sXp[2][0][ln] + sXp[3][0][ln] + bb;
    float Xf1 = sXp[0][1][ln] + sXp[1][1][ln] + sXp[2][1][ln] + sXp[3][1][ln] + bb;
    float Xf2 = sXp[0][2][ln] + sXp[1][2][ln] + sXp[2][2][ln] + sXp[3][2][ln] + bb;
    float Xf3 = sXp[0][3][ln] + sXp[1][3][ln] + sXp[2][3][ln] + sXp[3][3][ln] + bb;

    // ---- phase 3: h2[r][h] = relu(sum_o X[r][o] rw1[o][h] + rb1[h]) ----
    float c0, c1, c2, c3;
    c0 = c1 = c2 = c3 = rb1[tid];
    #pragma unroll   // full: immediate lane selects
    for (int i = 0; i < 64; i++) {
        float rwv = rw1[(i << 8) + tid];      // coalesced; L2-resident
        c0 = fmaf(rlane_imm(Xf0, i), rwv, c0);
        c1 = fmaf(rlane_imm(Xf1, i), rwv, c1);
        c2 = fmaf(rlane_imm(Xf2, i), rwv, c2);
        c3 = fmaf(rlane_imm(Xf3, i), rwv, c3);
    }
    c0 = fmaxf(c0, 0.f); c1 = fmaxf(c1, 0.f);
    c2 = fmaxf(c2, 0.f); c3 = fmaxf(c3, 0.f);

    // ---- phase 4: pre[r][c] = sum_h h2[r][h] rw2[h][c] ----
    {
        float2 r2 = ((const float2*)rw2)[tid];
        float p00 = c0 * r2.x, p01 = c0 * r2.y;
        float p10 = c1 * r2.x, p11 = c1 * r2.y;
        float p20 = c2 * r2.x, p21 = c2 * r2.y;
        float p30 = c3 * r2.x, p31 = c3 * r2.y;
        #pragma unroll
        for (int m = 32; m >= 1; m >>= 1) {
            p00 += __shfl_xor(p00, m); p01 += __shfl_xor(p01, m);
            p10 += __shfl_xor(p10, m); p11 += __shfl_xor(p11, m);
            p20 += __shfl_xor(p20, m); p21 += __shfl_xor(p21, m);
            p30 += __shfl_xor(p30, m); p31 += __shfl_xor(p31, m);
        }
        if (ln == 0) {
            sP4[wv][0][0] = p00; sP4[wv][0][1] = p01;
            sP4[wv][1][0] = p10; sP4[wv][1][1] = p11;
            sP4[wv][2][0] = p20; sP4[wv][2][1] = p21;
            sP4[wv][3][0] = p30; sP4[wv][3][1] = p31;
        }
    }
    __syncthreads();

    if (tid < GROWS * 2) {
        int r = tid >> 1, c = tid & 1;
        float pre = sP4[0][r][c] + sP4[1][r][c] + sP4[2][r][c] + sP4[3][r][c] + rb2[c];
        float a = 2.0f * tanhf(pre) + sbar[r][c];
        out[(b0 + r) * 2 + c] = a;   // unscaled; last block rescales if needed
        sa[tid] = a;
    }
    // Drain ALL block threads' out-writes to this XCD's L2 before the fence.
    __syncthreads();

    if (tid == 0) {
        float m = sa[0];
        #pragma unroll
        for (int i = 1; i < GROWS * 2; i++) m = fmaxf(m, sa[i]);
        atomicMax(&ws[0], fkey(m));
        __threadfence();                      // L2 writeback: out + key visible
        unsigned old = atomicAdd(&ws[1], 1u); // arrival counter
        sLast = (old == NBLOCKS - 1u);
    }
    __syncthreads();

    if (sLast) {
        __threadfence();
        unsigned k = atomicMax(&ws[0], 0u);   // read final key (0 <= any key)
        float scale = 2.0f / fkey_inv(k);
        if (scale < 1.0f) {
            for (int i = tid; i < 4096 * 2; i += 256) {
                float a = __hip_atomic_load(&out[i], __ATOMIC_RELAXED,
                                            __HIP_MEMORY_SCOPE_AGENT);
                out[i] = a * scale;
            }
        }
    }
}

extern "C" void kernel_launch(void* const* d_in, const int* in_sizes, int n_in,
                              void* d_out, int out_size, void* d_ws, size_t ws_size,
                              hipStream_t stream) {
    const float* x   = (const float*)d_in[0];
    const float* w1  = (const float*)d_in[1];
    const float* b1  = (const float*)d_in[2];
    const float* w2  = (const float*)d_in[3];
    const float* b2  = (const float*)d_in[4];
    const float* rw1 = (const float*)d_in[5];
    const float* rb1 = (const float*)d_in[6];
    const float* rw2 = (const float*)d_in[7];
    const float* rb2 = (const float*)d_in[8];
    float* out = (float*)d_out;
    unsigned* ws = (unsigned*)d_ws;

    // ws[0]=max key (0 < key(-inf): identity for max), ws[1]=arrival counter.
    hipMemsetAsync(d_ws, 0, 8, stream);
    barrier_net_fused<<<NBLOCKS, 256, 0, stream>>>(
        x, w1, b1, w2, b2, rw1, rb1, rw2, rb2, out, ws);
}

// Round 5
// 104.101 us; speedup vs baseline: 1.1135x; 1.1135x over previous
//
#include <hip/hip_runtime.h>
#include <math.h>

// Barrier_Net: deep-sets net + barrier + global max-rescale.
// R1: LDS broadcast storm (2112 ds_read/wave) ~45us. R2: s_load path ~40us.
// R3/R4: readlane (runtime & immediate idx) ~43/50us, VALUBusy 34%.
// Working theory after R4: all variants were INSTRUCTION-FETCH bound — fully
// unrolled ~24KB straight-line bodies stream through I$ once per wave.
// R5: small rolled loops (I$-resident) + uniform-address ds_read_b128
// broadcasts (free: same-address LDS read broadcasts, no immediate-lane-index
// requirement). Split into 3 kernels so per-dispatch counters attribute time.

#define NBLK 1024   // 4 rows/block, 4096 rows

__device__ __forceinline__ unsigned fkey(float f) {
    unsigned u = __float_as_uint(f);
    return (u & 0x80000000u) ? ~u : (u | 0x80000000u);
}
__device__ __forceinline__ float fkey_inv(unsigned k) {
    return __uint_as_float((k & 0x80000000u) ? (k & 0x7fffffffu) : ~k);
}

// ---------------- K1: phi layer 1 + neighbor sum + barrier term ----------------
__global__ __launch_bounds__(256, 4) void bn_phase1(
    const float* __restrict__ x,
    const float* __restrict__ w1, const float* __restrict__ b1,
    float* __restrict__ H, float* __restrict__ bar)
{
    __shared__ __align__(16) float sx[4][268];   // per-wave row buffer (66*4 + pad)

    const int tid = threadIdx.x;
    const int ln  = tid & 63;
    const int wv  = tid >> 6;
    const int row = blockIdx.x * 4 + wv;         // wave <-> batch row
    const float4* __restrict__ x4 = (const float4*)(x + (size_t)row * 264);

    // Two coalesced loads cover the whole row; stage into this wave's buffer.
    float4 xr = x4[ln];          // neighbor block n = ln
    float4 pv = x4[ln + 2];      // neighbor block n = ln+2 (also barrier data)
    ((float4*)sx[wv])[ln] = xr;
    if (ln >= 62) ((float4*)sx[wv])[ln + 2] = pv;   // slots 64, 65

    // per-lane weights: lane ln owns hidden units 4ln..4ln+3
    float4 w1r0 = ((const float4*)(w1      ))[ln];
    float4 w1r1 = ((const float4*)(w1 + 256))[ln];
    float4 w1r2 = ((const float4*)(w1 + 512))[ln];
    float4 w1r3 = ((const float4*)(w1 + 768))[ln];
    float4 b1r  = ((const float4*)b1)[ln];

    float a0 = 0.f, a1 = 0.f, a2 = 0.f, a3 = 0.f;
    // Rolled loop (I$-resident body). Uniform-address ds_read_b128 broadcast:
    // all 64 lanes read the same 16B -> conflict-free broadcast, no readlane.
    #pragma unroll 4
    for (int n = 0; n < 66; n++) {
        float4 xv = ((const float4*)sx[wv])[n];
        float h0 = b1r.x, h1 = b1r.y, h2 = b1r.z, h3 = b1r.w;
        h0 = fmaf(xv.x, w1r0.x, h0); h1 = fmaf(xv.x, w1r0.y, h1);
        h2 = fmaf(xv.x, w1r0.z, h2); h3 = fmaf(xv.x, w1r0.w, h3);
        h0 = fmaf(xv.y, w1r1.x, h0); h1 = fmaf(xv.y, w1r1.y, h1);
        h2 = fmaf(xv.y, w1r1.z, h2); h3 = fmaf(xv.y, w1r1.w, h3);
        h0 = fmaf(xv.z, w1r2.x, h0); h1 = fmaf(xv.z, w1r2.y, h1);
        h2 = fmaf(xv.z, w1r2.z, h2); h3 = fmaf(xv.z, w1r2.w, h3);
        h0 = fmaf(xv.w, w1r3.x, h0); h1 = fmaf(xv.w, w1r3.y, h1);
        h2 = fmaf(xv.w, w1r3.z, h2); h3 = fmaf(xv.w, w1r3.w, h3);
        a0 += fmaxf(h0, 0.f); a1 += fmaxf(h1, 0.f);
        a2 += fmaxf(h2, 0.f); a3 += fmaxf(h3, 0.f);
    }
    ((float4*)(H + (size_t)row * 256))[ln] = make_float4(a0, a1, a2, a3);

    // barrier term: lane ln <-> neighbor n = ln+2 (exactly 64 neighbors)
    {
        float px = pv.x, py = pv.y;
        float d  = sqrtf(px * px + py * py);
        float t  = d - 0.15f;
        float inv = 1.0f / (t * t);
        float bx = -px * inv, by = -py * inv;
        #pragma unroll
        for (int m = 32; m >= 1; m >>= 1) {
            bx += __shfl_xor(bx, m);
            by += __shfl_xor(by, m);
        }
        if (ln == 0) { bar[row * 2 + 0] = bx; bar[row * 2 + 1] = by; }
    }
}

// ---------------- K2: phi layer 2 (post-sum) + rho layers + block max ----------
__global__ __launch_bounds__(256, 4) void bn_phase234(
    const float* __restrict__ H, const float* __restrict__ bar,
    const float* __restrict__ w2,  const float* __restrict__ b2,
    const float* __restrict__ rw1, const float* __restrict__ rb1,
    const float* __restrict__ rw2, const float* __restrict__ rb2,
    float* __restrict__ out, unsigned* __restrict__ wskey)
{
    __shared__ __align__(16) float sH[4][264];
    __shared__ float sXp[4][4][68];   // [k-quarter wave][row][o]
    __shared__ __align__(16) float sX[4][68];
    __shared__ float sP4[4][4][2];
    __shared__ float sa[8];

    const int tid = threadIdx.x;
    const int ln  = tid & 63;
    const int wv  = tid >> 6;
    const int b0  = blockIdx.x * 4;

    // stage the 4 H rows (each wave loads its own row, coalesced)
    ((float4*)sH[wv])[ln] = ((const float4*)(H + (size_t)(b0 + wv) * 256))[ln];
    __syncthreads();

    // ---- phase 2: X[r][o] = sum_k H[r][k] w2[k][o] + 66 b2[o] ----
    // wave wv owns k-quarter [64wv,64wv+64); lane = o; H via uniform b128 reads.
    {
        float xp0 = 0.f, xp1 = 0.f, xp2 = 0.f, xp3 = 0.f;
        const float* w2q = w2 + (wv << 12);
        #pragma unroll 2
        for (int i = 0; i < 16; i++) {
            int kb = (wv << 4) + i;              // k-chunk (4 k's)
            float4 h0 = ((const float4*)sH[0])[kb];
            float4 h1 = ((const float4*)sH[1])[kb];
            float4 h2 = ((const float4*)sH[2])[kb];
            float4 h3 = ((const float4*)sH[3])[kb];
            float wk0 = w2q[((i << 2) + 0 << 6) + ln];
            float wk1 = w2q[((i << 2) + 1 << 6) + ln];
            float wk2 = w2q[((i << 2) + 2 << 6) + ln];
            float wk3 = w2q[((i << 2) + 3 << 6) + ln];
            xp0 = fmaf(h0.x, wk0, xp0); xp1 = fmaf(h1.x, wk0, xp1);
            xp2 = fmaf(h2.x, wk0, xp2); xp3 = fmaf(h3.x, wk0, xp3);
            xp0 = fmaf(h0.y, wk1, xp0); xp1 = fmaf(h1.y, wk1, xp1);
            xp2 = fmaf(h2.y, wk1, xp2); xp3 = fmaf(h3.y, wk1, xp3);
            xp0 = fmaf(h0.z, wk2, xp0); xp1 = fmaf(h1.z, wk2, xp1);
            xp2 = fmaf(h2.z, wk2, xp2); xp3 = fmaf(h3.z, wk2, xp3);
            xp0 = fmaf(h0.w, wk3, xp0); xp1 = fmaf(h1.w, wk3, xp1);
            xp2 = fmaf(h2.w, wk3, xp2); xp3 = fmaf(h3.w, wk3, xp3);
        }
        sXp[wv][0][ln] = xp0; sXp[wv][1][ln] = xp1;
        sXp[wv][2][ln] = xp2; sXp[wv][3][ln] = xp3;
    }
    __syncthreads();

    // wave wv folds row wv's partials -> sX[wv][ln]
    {
        float Xf = sXp[0][wv][ln] + sXp[1][wv][ln]
                 + sXp[2][wv][ln] + sXp[3][wv][ln] + 66.0f * b2[ln];
        sX[wv][ln] = Xf;
    }
    __syncthreads();

    // ---- phase 3: h2[r][h] = relu(sum_o X[r][o] rw1[o][h] + rb1[h]), h = tid ----
    float c0, c1, c2, c3;
    c0 = c1 = c2 = c3 = rb1[tid];
    #pragma unroll 2
    for (int i = 0; i < 16; i++) {
        float4 X0 = ((const float4*)sX[0])[i];
        float4 X1 = ((const float4*)sX[1])[i];
        float4 X2 = ((const float4*)sX[2])[i];
        float4 X3 = ((const float4*)sX[3])[i];
        float r0 = rw1[((i << 2) + 0 << 8) + tid];
        float r1 = rw1[((i << 2) + 1 << 8) + tid];
        float r2 = rw1[((i << 2) + 2 << 8) + tid];
        float r3 = rw1[((i << 2) + 3 << 8) + tid];
        c0 = fmaf(X0.x, r0, c0); c1 = fmaf(X1.x, r0, c1);
        c2 = fmaf(X2.x, r0, c2); c3 = fmaf(X3.x, r0, c3);
        c0 = fmaf(X0.y, r1, c0); c1 = fmaf(X1.y, r1, c1);
        c2 = fmaf(X2.y, r1, c2); c3 = fmaf(X3.y, r1, c3);
        c0 = fmaf(X0.z, r2, c0); c1 = fmaf(X1.z, r2, c1);
        c2 = fmaf(X2.z, r2, c2); c3 = fmaf(X3.z, r2, c3);
        c0 = fmaf(X0.w, r3, c0); c1 = fmaf(X1.w, r3, c1);
        c2 = fmaf(X2.w, r3, c2); c3 = fmaf(X3.w, r3, c3);
    }
    c0 = fmaxf(c0, 0.f); c1 = fmaxf(c1, 0.f);
    c2 = fmaxf(c2, 0.f); c3 = fmaxf(c3, 0.f);

    // ---- phase 4: pre[r][c] = sum_h h2[r][h] rw2[h][c]; butterfly over h ----
    {
        float2 r2v = ((const float2*)rw2)[tid];
        float p00 = c0 * r2v.x, p01 = c0 * r2v.y;
        float p10 = c1 * r2v.x, p11 = c1 * r2v.y;
        float p20 = c2 * r2v.x, p21 = c2 * r2v.y;
        float p30 = c3 * r2v.x, p31 = c3 * r2v.y;
        #pragma unroll
        for (int m = 32; m >= 1; m >>= 1) {
            p00 += __shfl_xor(p00, m); p01 += __shfl_xor(p01, m);
            p10 += __shfl_xor(p10, m); p11 += __shfl_xor(p11, m);
            p20 += __shfl_xor(p20, m); p21 += __shfl_xor(p21, m);
            p30 += __shfl_xor(p30, m); p31 += __shfl_xor(p31, m);
        }
        if (ln == 0) {
            sP4[wv][0][0] = p00; sP4[wv][0][1] = p01;
            sP4[wv][1][0] = p10; sP4[wv][1][1] = p11;
            sP4[wv][2][0] = p20; sP4[wv][2][1] = p21;
            sP4[wv][3][0] = p30; sP4[wv][3][1] = p31;
        }
    }
    __syncthreads();

    if (tid < 8) {
        int r = tid >> 1, c = tid & 1;
        float pre = sP4[0][r][c] + sP4[1][r][c] + sP4[2][r][c] + sP4[3][r][c] + rb2[c];
        float a = 2.0f * tanhf(pre) + bar[b0 * 2 + tid];
        out[b0 * 2 + tid] = a;
        sa[tid] = a;
    }
    __syncthreads();
    if (tid == 0) {
        float m = sa[0];
        #pragma unroll
        for (int i = 1; i < 8; i++) m = fmaxf(m, sa[i]);
        atomicMax(wskey, fkey(m));
    }
}

// ---------------- K3: conditional rescale ----------------
__global__ __launch_bounds__(256) void bn_scale(
    float* __restrict__ out, const unsigned* __restrict__ wskey)
{
    int i = blockIdx.x * 256 + threadIdx.x;
    float amax  = fkey_inv(*wskey);
    float scale = 2.0f / amax;
    float a = out[i];
    out[i] = (scale < 1.0f) ? a * scale : a;
}

extern "C" void kernel_launch(void* const* d_in, const int* in_sizes, int n_in,
                              void* d_out, int out_size, void* d_ws, size_t ws_size,
                              hipStream_t stream) {
    const float* x   = (const float*)d_in[0];
    const float* w1  = (const float*)d_in[1];
    const float* b1  = (const float*)d_in[2];
    const float* w2  = (const float*)d_in[3];
    const float* b2  = (const float*)d_in[4];
    const float* rw1 = (const float*)d_in[5];
    const float* rb1 = (const float*)d_in[6];
    const float* rw2 = (const float*)d_in[7];
    const float* rb2 = (const float*)d_in[8];
    float* out = (float*)d_out;

    // ws layout: [0,4): max key; [1024, 1024+4MB): H; then bar (32KB).
    unsigned* wskey = (unsigned*)d_ws;
    float* H   = (float*)((char*)d_ws + 1024);
    float* bar = (float*)((char*)d_ws + 1024 + (size_t)4096 * 256 * 4);

    hipMemsetAsync(d_ws, 0, 4, stream);   // key 0 < fkey(-inf): max identity
    bn_phase1<<<NBLK, 256, 0, stream>>>(x, w1, b1, H, bar);
    bn_phase234<<<NBLK, 256, 0, stream>>>(H, bar, w2, b2, rw1, rb1, rw2, rb2,
                                          out, wskey);
    bn_scale<<<8192 / 256, 256, 0, stream>>>(out, wskey);
}

// Round 6
// 95.225 us; speedup vs baseline: 1.2173x; 1.0932x over previous
//
#include <hip/hip_runtime.h>
#include <math.h>

// Barrier_Net: deep-sets net + barrier + global max-rescale.
// R1-R5 lesson: every data-path rewrite (LDS broadcast, s_load, readlane,
// b128 broadcast) was NEUTRAL — the hidden invariant was the same-address
// device-scope atomicMax from every block (512-1024 serialized cross-XCD
// RMWs ≈ 25-40 µs of drain, invisible in VALU/LDS/HBM counters; R4 added a
// 2nd same-address atomic and got 7 µs SLOWER).
// R6: no global atomics at all. Each K2 block stores its max to a distinct
// ws slot; K3 reduces the 1024 slots (L2-hot) and applies the scale.

#define NBLK 1024   // 4 rows/block, 4096 rows

__global__ __launch_bounds__(256, 4) void bn_phase1(
    const float* __restrict__ x,
    const float* __restrict__ w1, const float* __restrict__ b1,
    float* __restrict__ H, float* __restrict__ bar)
{
    __shared__ __align__(16) float sx[4][268];   // per-wave row buffer

    const int tid = threadIdx.x;
    const int ln  = tid & 63;
    const int wv  = tid >> 6;
    const int row = blockIdx.x * 4 + wv;         // wave <-> batch row
    const float4* __restrict__ x4 = (const float4*)(x + (size_t)row * 264);

    // Two coalesced loads cover the whole row; stage into this wave's buffer.
    float4 xr = x4[ln];          // neighbor block n = ln
    float4 pv = x4[ln + 2];      // neighbor block n = ln+2 (also barrier data)
    ((float4*)sx[wv])[ln] = xr;
    if (ln >= 62) ((float4*)sx[wv])[ln + 2] = pv;   // slots 64, 65

    // per-lane weights: lane ln owns hidden units 4ln..4ln+3
    float4 w1r0 = ((const float4*)(w1      ))[ln];
    float4 w1r1 = ((const float4*)(w1 + 256))[ln];
    float4 w1r2 = ((const float4*)(w1 + 512))[ln];
    float4 w1r3 = ((const float4*)(w1 + 768))[ln];
    float4 b1r  = ((const float4*)b1)[ln];

    float a0 = 0.f, a1 = 0.f, a2 = 0.f, a3 = 0.f;
    // Rolled loop; uniform-address ds_read_b128 = conflict-free broadcast.
    #pragma unroll 4
    for (int n = 0; n < 66; n++) {
        float4 xv = ((const float4*)sx[wv])[n];
        float h0 = b1r.x, h1 = b1r.y, h2 = b1r.z, h3 = b1r.w;
        h0 = fmaf(xv.x, w1r0.x, h0); h1 = fmaf(xv.x, w1r0.y, h1);
        h2 = fmaf(xv.x, w1r0.z, h2); h3 = fmaf(xv.x, w1r0.w, h3);
        h0 = fmaf(xv.y, w1r1.x, h0); h1 = fmaf(xv.y, w1r1.y, h1);
        h2 = fmaf(xv.y, w1r1.z, h2); h3 = fmaf(xv.y, w1r1.w, h3);
        h0 = fmaf(xv.z, w1r2.x, h0); h1 = fmaf(xv.z, w1r2.y, h1);
        h2 = fmaf(xv.z, w1r2.z, h2); h3 = fmaf(xv.z, w1r2.w, h3);
        h0 = fmaf(xv.w, w1r3.x, h0); h1 = fmaf(xv.w, w1r3.y, h1);
        h2 = fmaf(xv.w, w1r3.z, h2); h3 = fmaf(xv.w, w1r3.w, h3);
        a0 += fmaxf(h0, 0.f); a1 += fmaxf(h1, 0.f);
        a2 += fmaxf(h2, 0.f); a3 += fmaxf(h3, 0.f);
    }
    ((float4*)(H + (size_t)row * 256))[ln] = make_float4(a0, a1, a2, a3);

    // barrier term: lane ln <-> neighbor n = ln+2 (exactly 64 neighbors)
    {
        float px = pv.x, py = pv.y;
        float d  = sqrtf(px * px + py * py);
        float t  = d - 0.15f;
        float inv = 1.0f / (t * t);
        float bx = -px * inv, by = -py * inv;
        #pragma unroll
        for (int m = 32; m >= 1; m >>= 1) {
            bx += __shfl_xor(bx, m);
            by += __shfl_xor(by, m);
        }
        if (ln == 0) { bar[row * 2 + 0] = bx; bar[row * 2 + 1] = by; }
    }
}

__global__ __launch_bounds__(256, 4) void bn_phase234(
    const float* __restrict__ H, const float* __restrict__ bar,
    const float* __restrict__ w2,  const float* __restrict__ b2,
    const float* __restrict__ rw1, const float* __restrict__ rb1,
    const float* __restrict__ rw2, const float* __restrict__ rb2,
    float* __restrict__ out, float* __restrict__ blkmax)
{
    __shared__ __align__(16) float sH[4][264];
    __shared__ float sXp[4][4][68];   // [k-quarter wave][row][o]
    __shared__ __align__(16) float sX[4][68];
    __shared__ float sP4[4][4][2];
    __shared__ float sa[8];

    const int tid = threadIdx.x;
    const int ln  = tid & 63;
    const int wv  = tid >> 6;
    const int b0  = blockIdx.x * 4;

    ((float4*)sH[wv])[ln] = ((const float4*)(H + (size_t)(b0 + wv) * 256))[ln];
    __syncthreads();

    // ---- phase 2: X[r][o] = sum_k H[r][k] w2[k][o] + 66 b2[o] ----
    {
        float xp0 = 0.f, xp1 = 0.f, xp2 = 0.f, xp3 = 0.f;
        const float* w2q = w2 + (wv << 12);
        #pragma unroll 2
        for (int i = 0; i < 16; i++) {
            int kb = (wv << 4) + i;
            float4 h0 = ((const float4*)sH[0])[kb];
            float4 h1 = ((const float4*)sH[1])[kb];
            float4 h2 = ((const float4*)sH[2])[kb];
            float4 h3 = ((const float4*)sH[3])[kb];
            float wk0 = w2q[(((i << 2) + 0) << 6) + ln];
            float wk1 = w2q[(((i << 2) + 1) << 6) + ln];
            float wk2 = w2q[(((i << 2) + 2) << 6) + ln];
            float wk3 = w2q[(((i << 2) + 3) << 6) + ln];
            xp0 = fmaf(h0.x, wk0, xp0); xp1 = fmaf(h1.x, wk0, xp1);
            xp2 = fmaf(h2.x, wk0, xp2); xp3 = fmaf(h3.x, wk0, xp3);
            xp0 = fmaf(h0.y, wk1, xp0); xp1 = fmaf(h1.y, wk1, xp1);
            xp2 = fmaf(h2.y, wk1, xp2); xp3 = fmaf(h3.y, wk1, xp3);
            xp0 = fmaf(h0.z, wk2, xp0); xp1 = fmaf(h1.z, wk2, xp1);
            xp2 = fmaf(h2.z, wk2, xp2); xp3 = fmaf(h3.z, wk2, xp3);
            xp0 = fmaf(h0.w, wk3, xp0); xp1 = fmaf(h1.w, wk3, xp1);
            xp2 = fmaf(h2.w, wk3, xp2); xp3 = fmaf(h3.w, wk3, xp3);
        }
        sXp[wv][0][ln] = xp0; sXp[wv][1][ln] = xp1;
        sXp[wv][2][ln] = xp2; sXp[wv][3][ln] = xp3;
    }
    __syncthreads();

    {
        float Xf = sXp[0][wv][ln] + sXp[1][wv][ln]
                 + sXp[2][wv][ln] + sXp[3][wv][ln] + 66.0f * b2[ln];
        sX[wv][ln] = Xf;
    }
    __syncthreads();

    // ---- phase 3: h2[r][h] = relu(sum_o X[r][o] rw1[o][h] + rb1[h]) ----
    float c0, c1, c2, c3;
    c0 = c1 = c2 = c3 = rb1[tid];
    #pragma unroll 2
    for (int i = 0; i < 16; i++) {
        float4 X0 = ((const float4*)sX[0])[i];
        float4 X1 = ((const float4*)sX[1])[i];
        float4 X2 = ((const float4*)sX[2])[i];
        float4 X3 = ((const float4*)sX[3])[i];
        float r0 = rw1[(((i << 2) + 0) << 8) + tid];
        float r1 = rw1[(((i << 2) + 1) << 8) + tid];
        float r2 = rw1[(((i << 2) + 2) << 8) + tid];
        float r3 = rw1[(((i << 2) + 3) << 8) + tid];
        c0 = fmaf(X0.x, r0, c0); c1 = fmaf(X1.x, r0, c1);
        c2 = fmaf(X2.x, r0, c2); c3 = fmaf(X3.x, r0, c3);
        c0 = fmaf(X0.y, r1, c0); c1 = fmaf(X1.y, r1, c1);
        c2 = fmaf(X2.y, r1, c2); c3 = fmaf(X3.y, r1, c3);
        c0 = fmaf(X0.z, r2, c0); c1 = fmaf(X1.z, r2, c1);
        c2 = fmaf(X2.z, r2, c2); c3 = fmaf(X3.z, r2, c3);
        c0 = fmaf(X0.w, r3, c0); c1 = fmaf(X1.w, r3, c1);
        c2 = fmaf(X2.w, r3, c2); c3 = fmaf(X3.w, r3, c3);
    }
    c0 = fmaxf(c0, 0.f); c1 = fmaxf(c1, 0.f);
    c2 = fmaxf(c2, 0.f); c3 = fmaxf(c3, 0.f);

    // ---- phase 4: pre[r][c] = sum_h h2[r][h] rw2[h][c]; butterfly over h ----
    {
        float2 r2v = ((const float2*)rw2)[tid];
        float p00 = c0 * r2v.x, p01 = c0 * r2v.y;
        float p10 = c1 * r2v.x, p11 = c1 * r2v.y;
        float p20 = c2 * r2v.x, p21 = c2 * r2v.y;
        float p30 = c3 * r2v.x, p31 = c3 * r2v.y;
        #pragma unroll
        for (int m = 32; m >= 1; m >>= 1) {
            p00 += __shfl_xor(p00, m); p01 += __shfl_xor(p01, m);
            p10 += __shfl_xor(p10, m); p11 += __shfl_xor(p11, m);
            p20 += __shfl_xor(p20, m); p21 += __shfl_xor(p21, m);
            p30 += __shfl_xor(p30, m); p31 += __shfl_xor(p31, m);
        }
        if (ln == 0) {
            sP4[wv][0][0] = p00; sP4[wv][0][1] = p01;
            sP4[wv][1][0] = p10; sP4[wv][1][1] = p11;
            sP4[wv][2][0] = p20; sP4[wv][2][1] = p21;
            sP4[wv][3][0] = p30; sP4[wv][3][1] = p31;
        }
    }
    __syncthreads();

    if (tid < 8) {
        int r = tid >> 1, c = tid & 1;
        float pre = sP4[0][r][c] + sP4[1][r][c] + sP4[2][r][c] + sP4[3][r][c] + rb2[c];
        float a = 2.0f * tanhf(pre) + bar[b0 * 2 + tid];
        out[b0 * 2 + tid] = a;
        sa[tid] = a;
    }
    __syncthreads();
    // NO global atomic: block max -> distinct slot (plain store, no contention)
    if (tid == 0) {
        float m = sa[0];
        #pragma unroll
        for (int i = 1; i < 8; i++) m = fmaxf(m, sa[i]);
        blkmax[blockIdx.x] = m;
    }
}

// ---- K3: reduce 1024 block maxima (L2-hot) + conditional rescale ----
__global__ __launch_bounds__(256) void bn_scale(
    float* __restrict__ out, const float* __restrict__ blkmax)
{
    __shared__ float sm[4];
    const int tid = threadIdx.x;
    const int ln  = tid & 63;
    const int wv  = tid >> 6;

    float m = fmaxf(fmaxf(blkmax[tid], blkmax[tid + 256]),
                    fmaxf(blkmax[tid + 512], blkmax[tid + 768]));
    #pragma unroll
    for (int s = 32; s >= 1; s >>= 1) m = fmaxf(m, __shfl_xor(m, s));
    if (ln == 0) sm[wv] = m;
    __syncthreads();
    float amax = fmaxf(fmaxf(sm[0], sm[1]), fmaxf(sm[2], sm[3]));

    float scale = 2.0f / amax;
    int i = blockIdx.x * 256 + tid;
    float a = out[i];
    out[i] = (scale < 1.0f) ? a * scale : a;
}

extern "C" void kernel_launch(void* const* d_in, const int* in_sizes, int n_in,
                              void* d_out, int out_size, void* d_ws, size_t ws_size,
                              hipStream_t stream) {
    const float* x   = (const float*)d_in[0];
    const float* w1  = (const float*)d_in[1];
    const float* b1  = (const float*)d_in[2];
    const float* w2  = (const float*)d_in[3];
    const float* b2  = (const float*)d_in[4];
    const float* rw1 = (const float*)d_in[5];
    const float* rb1 = (const float*)d_in[6];
    const float* rw2 = (const float*)d_in[7];
    const float* rb2 = (const float*)d_in[8];
    float* out = (float*)d_out;

    // ws layout: [0,4KB): blkmax[1024]; [4KB, 4KB+4MB): H; then bar (32KB).
    float* blkmax = (float*)d_ws;
    float* H      = (float*)((char*)d_ws + 4096);
    float* bar    = (float*)((char*)d_ws + 4096 + (size_t)4096 * 256 * 4);

    bn_phase1<<<NBLK, 256, 0, stream>>>(x, w1, b1, H, bar);
    bn_phase234<<<NBLK, 256, 0, stream>>>(H, bar, w2, b2, rw1, rb1, rw2, rb2,
                                          out, blkmax);
    bn_scale<<<8192 / 256, 256, 0, stream>>>(out, blkmax);
}

// Round 7
// 89.759 us; speedup vs baseline: 1.2914x; 1.0609x over previous
//
#include <hip/hip_runtime.h>
#include <math.h>

// Barrier_Net: deep-sets net + barrier + global max-rescale.
// R1-R5: every data-path rewrite neutral; R6 WIN: the same-address
// device-scope atomicMax storm was the hidden serializer (-9 us).
// Top-5 is now 100% harness poison fills (256 MiB ws fill = 41 us, fixed).
// R7: the whole net is per-row — only the max-rescale couples rows. Fuse
// phases 1-4 into ONE kernel (H stays in LDS; kills the 4 MB H round-trip
// and one dispatch+graph gap). 2 dispatches total, no atomics, no memset.

#define NBLK 1024   // 4 rows/block (wave <-> row), 4096 rows

__global__ __launch_bounds__(256, 4) void bn_row(
    const float* __restrict__ x,
    const float* __restrict__ w1,  const float* __restrict__ b1,
    const float* __restrict__ w2,  const float* __restrict__ b2,
    const float* __restrict__ rw1, const float* __restrict__ rb1,
    const float* __restrict__ rw2, const float* __restrict__ rb2,
    float* __restrict__ out, float* __restrict__ blkmax)
{
    __shared__ __align__(16) float sx[4][268];   // per-wave row buffer
    __shared__ __align__(16) float sH[4][264];   // per-row summed hidden
    __shared__ float sXp[4][4][68];              // [k-quarter][row][o]
    __shared__ __align__(16) float sX[4][68];    // per-row phi-sum
    __shared__ float sP4[4][4][2];               // [wave][row][c]
    __shared__ float sbar[4][2];
    __shared__ float sa[8];

    const int tid = threadIdx.x;
    const int ln  = tid & 63;
    const int wv  = tid >> 6;
    const int b0  = blockIdx.x * 4;
    const int row = b0 + wv;                     // wave <-> batch row
    const float4* __restrict__ x4 = (const float4*)(x + (size_t)row * 264);

    // Two coalesced loads cover the whole row; stage into this wave's buffer.
    float4 xr = x4[ln];          // neighbor block n = ln
    float4 pv = x4[ln + 2];      // neighbor block n = ln+2 (also barrier data)
    ((float4*)sx[wv])[ln] = xr;
    if (ln >= 62) ((float4*)sx[wv])[ln + 2] = pv;   // slots 64, 65

    // ---- phase 1: lane ln owns hidden units 4ln..4ln+3 ----
    float4 w1r0 = ((const float4*)(w1      ))[ln];
    float4 w1r1 = ((const float4*)(w1 + 256))[ln];
    float4 w1r2 = ((const float4*)(w1 + 512))[ln];
    float4 w1r3 = ((const float4*)(w1 + 768))[ln];
    float4 b1r  = ((const float4*)b1)[ln];

    float a0 = 0.f, a1 = 0.f, a2 = 0.f, a3 = 0.f;
    // Rolled loop; uniform-address ds_read_b128 = conflict-free broadcast.
    #pragma unroll 4
    for (int n = 0; n < 66; n++) {
        float4 xv = ((const float4*)sx[wv])[n];
        float h0 = b1r.x, h1 = b1r.y, h2 = b1r.z, h3 = b1r.w;
        h0 = fmaf(xv.x, w1r0.x, h0); h1 = fmaf(xv.x, w1r0.y, h1);
        h2 = fmaf(xv.x, w1r0.z, h2); h3 = fmaf(xv.x, w1r0.w, h3);
        h0 = fmaf(xv.y, w1r1.x, h0); h1 = fmaf(xv.y, w1r1.y, h1);
        h2 = fmaf(xv.y, w1r1.z, h2); h3 = fmaf(xv.y, w1r1.w, h3);
        h0 = fmaf(xv.z, w1r2.x, h0); h1 = fmaf(xv.z, w1r2.y, h1);
        h2 = fmaf(xv.z, w1r2.z, h2); h3 = fmaf(xv.z, w1r2.w, h3);
        h0 = fmaf(xv.w, w1r3.x, h0); h1 = fmaf(xv.w, w1r3.y, h1);
        h2 = fmaf(xv.w, w1r3.z, h2); h3 = fmaf(xv.w, w1r3.w, h3);
        a0 += fmaxf(h0, 0.f); a1 += fmaxf(h1, 0.f);
        a2 += fmaxf(h2, 0.f); a3 += fmaxf(h3, 0.f);
    }
    ((float4*)sH[wv])[ln] = make_float4(a0, a1, a2, a3);   // stays in LDS

    // barrier term: lane ln <-> neighbor n = ln+2 (exactly 64 neighbors)
    {
        float px = pv.x, py = pv.y;
        float d  = sqrtf(px * px + py * py);
        float t  = d - 0.15f;
        float inv = 1.0f / (t * t);
        float bx = -px * inv, by = -py * inv;
        #pragma unroll
        for (int m = 32; m >= 1; m >>= 1) {
            bx += __shfl_xor(bx, m);
            by += __shfl_xor(by, m);
        }
        if (ln == 0) { sbar[wv][0] = bx; sbar[wv][1] = by; }
    }
    __syncthreads();

    // ---- phase 2: X[r][o] = sum_k H[r][k] w2[k][o] + 66 b2[o] ----
    // wave wv owns k-quarter [64wv,64wv+64); lane = o.
    {
        float xp0 = 0.f, xp1 = 0.f, xp2 = 0.f, xp3 = 0.f;
        const float* w2q = w2 + (wv << 12);
        #pragma unroll 2
        for (int i = 0; i < 16; i++) {
            int kb = (wv << 4) + i;
            float4 h0 = ((const float4*)sH[0])[kb];
            float4 h1 = ((const float4*)sH[1])[kb];
            float4 h2 = ((const float4*)sH[2])[kb];
            float4 h3 = ((const float4*)sH[3])[kb];
            float wk0 = w2q[(((i << 2) + 0) << 6) + ln];
            float wk1 = w2q[(((i << 2) + 1) << 6) + ln];
            float wk2 = w2q[(((i << 2) + 2) << 6) + ln];
            float wk3 = w2q[(((i << 2) + 3) << 6) + ln];
            xp0 = fmaf(h0.x, wk0, xp0); xp1 = fmaf(h1.x, wk0, xp1);
            xp2 = fmaf(h2.x, wk0, xp2); xp3 = fmaf(h3.x, wk0, xp3);
            xp0 = fmaf(h0.y, wk1, xp0); xp1 = fmaf(h1.y, wk1, xp1);
            xp2 = fmaf(h2.y, wk1, xp2); xp3 = fmaf(h3.y, wk1, xp3);
            xp0 = fmaf(h0.z, wk2, xp0); xp1 = fmaf(h1.z, wk2, xp1);
            xp2 = fmaf(h2.z, wk2, xp2); xp3 = fmaf(h3.z, wk2, xp3);
            xp0 = fmaf(h0.w, wk3, xp0); xp1 = fmaf(h1.w, wk3, xp1);
            xp2 = fmaf(h2.w, wk3, xp2); xp3 = fmaf(h3.w, wk3, xp3);
        }
        sXp[wv][0][ln] = xp0; sXp[wv][1][ln] = xp1;
        sXp[wv][2][ln] = xp2; sXp[wv][3][ln] = xp3;
    }
    __syncthreads();

    {
        float Xf = sXp[0][wv][ln] + sXp[1][wv][ln]
                 + sXp[2][wv][ln] + sXp[3][wv][ln] + 66.0f * b2[ln];
        sX[wv][ln] = Xf;
    }
    __syncthreads();

    // ---- phase 3: h2[r][h] = relu(sum_o X[r][o] rw1[o][h] + rb1[h]) ----
    float c0, c1, c2, c3;
    c0 = c1 = c2 = c3 = rb1[tid];
    #pragma unroll 2
    for (int i = 0; i < 16; i++) {
        float4 X0 = ((const float4*)sX[0])[i];
        float4 X1 = ((const float4*)sX[1])[i];
        float4 X2 = ((const float4*)sX[2])[i];
        float4 X3 = ((const float4*)sX[3])[i];
        float r0 = rw1[(((i << 2) + 0) << 8) + tid];
        float r1 = rw1[(((i << 2) + 1) << 8) + tid];
        float r2 = rw1[(((i << 2) + 2) << 8) + tid];
        float r3 = rw1[(((i << 2) + 3) << 8) + tid];
        c0 = fmaf(X0.x, r0, c0); c1 = fmaf(X1.x, r0, c1);
        c2 = fmaf(X2.x, r0, c2); c3 = fmaf(X3.x, r0, c3);
        c0 = fmaf(X0.y, r1, c0); c1 = fmaf(X1.y, r1, c1);
        c2 = fmaf(X2.y, r1, c2); c3 = fmaf(X3.y, r1, c3);
        c0 = fmaf(X0.z, r2, c0); c1 = fmaf(X1.z, r2, c1);
        c2 = fmaf(X2.z, r2, c2); c3 = fmaf(X3.z, r2, c3);
        c0 = fmaf(X0.w, r3, c0); c1 = fmaf(X1.w, r3, c1);
        c2 = fmaf(X2.w, r3, c2); c3 = fmaf(X3.w, r3, c3);
    }
    c0 = fmaxf(c0, 0.f); c1 = fmaxf(c1, 0.f);
    c2 = fmaxf(c2, 0.f); c3 = fmaxf(c3, 0.f);

    // ---- phase 4: pre[r][c] = sum_h h2[r][h] rw2[h][c]; butterfly over h ----
    {
        float2 r2v = ((const float2*)rw2)[tid];
        float p00 = c0 * r2v.x, p01 = c0 * r2v.y;
        float p10 = c1 * r2v.x, p11 = c1 * r2v.y;
        float p20 = c2 * r2v.x, p21 = c2 * r2v.y;
        float p30 = c3 * r2v.x, p31 = c3 * r2v.y;
        #pragma unroll
        for (int m = 32; m >= 1; m >>= 1) {
            p00 += __shfl_xor(p00, m); p01 += __shfl_xor(p01, m);
            p10 += __shfl_xor(p10, m); p11 += __shfl_xor(p11, m);
            p20 += __shfl_xor(p20, m); p21 += __shfl_xor(p21, m);
            p30 += __shfl_xor(p30, m); p31 += __shfl_xor(p31, m);
        }
        if (ln == 0) {
            sP4[wv][0][0] = p00; sP4[wv][0][1] = p01;
            sP4[wv][1][0] = p10; sP4[wv][1][1] = p11;
            sP4[wv][2][0] = p20; sP4[wv][2][1] = p21;
            sP4[wv][3][0] = p30; sP4[wv][3][1] = p31;
        }
    }
    __syncthreads();

    if (tid < 8) {
        int r = tid >> 1, c = tid & 1;
        float pre = sP4[0][r][c] + sP4[1][r][c] + sP4[2][r][c] + sP4[3][r][c] + rb2[c];
        float a = 2.0f * tanhf(pre) + sbar[r][c];
        out[b0 * 2 + tid] = a;
        sa[tid] = a;
    }
    __syncthreads();
    // No global atomic: block max -> distinct slot (plain store).
    if (tid == 0) {
        float m = sa[0];
        #pragma unroll
        for (int i = 1; i < 8; i++) m = fmaxf(m, sa[i]);
        blkmax[blockIdx.x] = m;
    }
}

// ---- K2: reduce 1024 block maxima (L2-hot) + conditional rescale ----
__global__ __launch_bounds__(256) void bn_scale(
    float* __restrict__ out, const float* __restrict__ blkmax)
{
    __shared__ float sm[4];
    const int tid = threadIdx.x;
    const int ln  = tid & 63;
    const int wv  = tid >> 6;

    float m = fmaxf(fmaxf(blkmax[tid], blkmax[tid + 256]),
                    fmaxf(blkmax[tid + 512], blkmax[tid + 768]));
    #pragma unroll
    for (int s = 32; s >= 1; s >>= 1) m = fmaxf(m, __shfl_xor(m, s));
    if (ln == 0) sm[wv] = m;
    __syncthreads();
    float amax = fmaxf(fmaxf(sm[0], sm[1]), fmaxf(sm[2], sm[3]));

    float scale = 2.0f / amax;
    int i = blockIdx.x * 256 + tid;
    float a = out[i];
    out[i] = (scale < 1.0f) ? a * scale : a;
}

extern "C" void kernel_launch(void* const* d_in, const int* in_sizes, int n_in,
                              void* d_out, int out_size, void* d_ws, size_t ws_size,
                              hipStream_t stream) {
    const float* x   = (const float*)d_in[0];
    const float* w1  = (const float*)d_in[1];
    const float* b1  = (const float*)d_in[2];
    const float* w2  = (const float*)d_in[3];
    const float* b2  = (const float*)d_in[4];
    const float* rw1 = (const float*)d_in[5];
    const float* rb1 = (const float*)d_in[6];
    const float* rw2 = (const float*)d_in[7];
    const float* rb2 = (const float*)d_in[8];
    float* out = (float*)d_out;
    float* blkmax = (float*)d_ws;   // 1024 distinct slots, no init needed

    bn_row<<<NBLK, 256, 0, stream>>>(x, w1, b1, w2, b2, rw1, rb1, rw2, rb2,
                                     out, blkmax);
    bn_scale<<<8192 / 256, 256, 0, stream>>>(out, blkmax);
}